// Round 4
// baseline (1093.609 us; speedup 1.0000x reference)
//
#include <hip/hip_runtime.h>
#include <hip/hip_cooperative_groups.h>
#include <cstdint>
#include <cstddef>

namespace cg = cooperative_groups;

#define NN 512
#define MM 256
#define ZT 1e-9f
#define CAP 16384
#define NPL 216          // 24 L1 planes + 192 L2 planes
#define NTHR 131072      // 256 blocks * 512 threads
#define NWV 2048         // waves

struct Params {
  const float *x, *S, *wEV1, *wLSI1, *b1, *wEV2, *wLSI2, *b2, *W1, *bW1, *W2, *bW2;
  float *out;
  int *sp_cnt, *s_cnt, *sp_ptr, *s_ptr, *sp_cols, *sp_rows, *s_cols;
  float *s_vals, *wpk, *xt, *u1, *u2, *zA1, *zB1, *y1, *zA2, *zB2, *zacc, *v1, *v2, *y2, *ht;
};

// one CSR row x 64-batch MAC; weights stream contiguously (packed), z scattered L2/L3
__device__ inline float row_mac(const int* __restrict__ cols, const float* __restrict__ wv,
                                int jb, int je, const float* __restrict__ zin, int lane) {
  float acc = 0.f;
  for (int j0 = jb; j0 < je; j0 += 8) {
    float w8[8], z8[8];
#pragma unroll
    for (int i = 0; i < 8; ++i) {
      int j = j0 + i;
      bool v = (j < je);
      int js = v ? j : jb;
      int c = cols[js];
      w8[i] = v ? wv[js] : 0.f;
      z8[i] = zin[(c << 6) + lane];
    }
#pragma unroll
    for (int i = 0; i < 8; ++i) acc += w8[i] * z8[i];
  }
  return acc;
}

__global__ __launch_bounds__(512, 1) void mega(Params P) {
  cg::grid_group grid = cg::this_grid();
  const int tid = threadIdx.x;
  const int gtid = blockIdx.x * 512 + tid;
  const int W = gtid >> 6;
  const int lane = tid & 63;

  // ---- P0: transpose x -> xt[n][b]  +  sparsity counts ----
  if (gtid < 32768) {
    int n = gtid >> 6, b = gtid & 63;
    P.xt[gtid] = P.x[b * NN + n];
  }
  if (W >= 512 && W < 1024) {
    int m = W - 512;
    int csp = 0, cs = 0;
    for (int ch = 0; ch < 8; ++ch) {
      int n = ch * 64 + lane;
      float s = P.S[m * NN + n];
      bool ps  = (s != 0.f);
      bool psp = ((fabsf(s) + ((m == n) ? 1.f : 0.f)) > ZT) && !((m >= MM) && (n >= MM));
      csp += __popcll(__ballot(psp));
      cs  += __popcll(__ballot(ps));
    }
    if (lane == 0) { P.sp_cnt[m] = csp; P.s_cnt[m] = cs; }
  }
  grid.sync();

  // ---- P1: exclusive scan (wave 0) ----
  if (W == 0) {
    int c0[8], c1[8]; int t0 = 0, t1 = 0;
    for (int i = 0; i < 8; ++i) {
      c0[i] = P.sp_cnt[lane * 8 + i]; t0 += c0[i];
      c1[i] = P.s_cnt[lane * 8 + i];  t1 += c1[i];
    }
    int i0 = t0, i1 = t1;
    for (int d = 1; d < 64; d <<= 1) {
      int x0 = __shfl_up(i0, d), x1 = __shfl_up(i1, d);
      if (lane >= d) { i0 += x0; i1 += x1; }
    }
    int e0 = i0 - t0, e1 = i1 - t1;
    for (int i = 0; i < 8; ++i) {
      P.sp_ptr[lane * 8 + i] = e0; e0 += c0[i];
      P.s_ptr[lane * 8 + i]  = e1; e1 += c1[i];
    }
    if (lane == 63) { P.sp_ptr[NN] = e0; P.s_ptr[NN] = e1; }
  }
  grid.sync();

  // ---- P2: CSR fill ----
  if (W < 512) {
    int m = W;
    int bsp = P.sp_ptr[m], bs = P.s_ptr[m];
    unsigned long long lt = (1ull << lane) - 1ull;
    for (int ch = 0; ch < 8; ++ch) {
      int n = ch * 64 + lane;
      float s = P.S[m * NN + n];
      bool ps  = (s != 0.f);
      bool psp = ((fabsf(s) + ((m == n) ? 1.f : 0.f)) > ZT) && !((m >= MM) && (n >= MM));
      unsigned long long msp = __ballot(psp), ms = __ballot(ps);
      if (psp) { int p = bsp + __popcll(msp & lt); if (p < CAP) { P.sp_cols[p] = n; P.sp_rows[p] = m; } }
      if (ps)  { int p = bs  + __popcll(ms  & lt); if (p < CAP) { P.s_cols[p] = n; P.s_vals[p] = s; } }
      bsp += __popcll(msp); bs += __popcll(ms);
    }
  }
  grid.sync();

  // ---- P3: pack masked weights, job = (j, plane) interleaved for max MLP ----
  {
    int nnz = P.sp_ptr[NN];
    int total = nnz * NPL;
    for (int t = gtid; t < total; t += NTHR) {
      int j = t / NPL, p = t - j * NPL;
      int rv = P.sp_rows[j], cv = P.sp_cols[j];
      const float* src = (p < 24) ? (P.wEV1 + ((size_t)p << 18))
                                  : (P.wEV2 + ((size_t)(p - 24) << 18));
      P.wpk[(size_t)p * CAP + j] = src[(rv << 9) + cv];
    }
  }
  grid.sync();

  // ---- P4: L1 k0 (zA1 = Phi0 x) + LSI u1 = S x ----
  for (int u = W; u < 4608; u += NWV) {
    if (u < 4096) {
      int f = u >> 9, r = u & 511;
      const float* wv = P.wpk + (size_t)(f * 3 + 0) * CAP;
      float a = row_mac(P.sp_cols, wv, P.sp_ptr[r], P.sp_ptr[r + 1], P.xt, lane);
      P.zA1[(((size_t)f << 9) + r << 6) + lane] = a;
    } else {
      int r = u - 4096;
      float a = row_mac(P.s_cols, P.s_vals, P.s_ptr[r], P.s_ptr[r + 1], P.xt, lane);
      P.u1[(r << 6) + lane] = a;
    }
  }
  grid.sync();

  // ---- P5: L1 k1 (zB1 = Phi1 zA1) + u2 = S u1 ----
  for (int u = W; u < 4608; u += NWV) {
    if (u < 4096) {
      int f = u >> 9, r = u & 511;
      const float* wv = P.wpk + (size_t)(f * 3 + 1) * CAP;
      float a = row_mac(P.sp_cols, wv, P.sp_ptr[r], P.sp_ptr[r + 1], P.zA1 + ((size_t)f << 15), lane);
      P.zB1[(((size_t)f << 9) + r << 6) + lane] = a;
    } else {
      int r = u - 4096;
      float a = row_mac(P.s_cols, P.s_vals, P.s_ptr[r], P.s_ptr[r + 1], P.u1, lane);
      P.u2[(r << 6) + lane] = a;
    }
  }
  grid.sync();

  // ---- P6: L1 k2 + combine -> y1 ----
  for (int u = W; u < 4096; u += NWV) {
    int f = u >> 9, r = u & 511;
    const float* wv = P.wpk + (size_t)(f * 3 + 2) * CAP;
    float a = row_mac(P.sp_cols, wv, P.sp_ptr[r], P.sp_ptr[r + 1], P.zB1 + ((size_t)f << 15), lane);
    int mb = (r << 6) + lane;
    size_t idx = ((size_t)f << 15) + mb;
    P.y1[idx] = P.zA1[idx] + P.zB1[idx] + a
              + P.wLSI1[f * 3 + 0] * P.xt[mb] + P.wLSI1[f * 3 + 1] * P.u1[mb]
              + P.wLSI1[f * 3 + 2] * P.u2[mb] + P.b1[f];
  }
  grid.sync();

  // ---- P7: L2 k0 (zA2 = Phi0 y1_g, zacc = zA2) + v1 = S y1_g ----
  for (int u = W; u < 36864; u += NWV) {
    if (u < 32768) {
      int c = u >> 9, r = u & 511;
      int f = c >> 3, g = c & 7;
      const float* wv = P.wpk + (size_t)(24 + (f * 3 + 0) * 8 + g) * CAP;
      float a = row_mac(P.sp_cols, wv, P.sp_ptr[r], P.sp_ptr[r + 1], P.y1 + ((size_t)g << 15), lane);
      size_t idx = ((size_t)c << 15) + (r << 6) + lane;
      P.zA2[idx] = a; P.zacc[idx] = a;
    } else {
      int t = u - 32768; int g = t >> 9, r = t & 511;
      float a = row_mac(P.s_cols, P.s_vals, P.s_ptr[r], P.s_ptr[r + 1], P.y1 + ((size_t)g << 15), lane);
      P.v1[((size_t)g << 15) + (r << 6) + lane] = a;
    }
  }
  grid.sync();

  // ---- P8: L2 k1 (zB2 = Phi1 zA2, zacc +=) + v2 = S v1_g ----
  for (int u = W; u < 36864; u += NWV) {
    if (u < 32768) {
      int c = u >> 9, r = u & 511;
      int f = c >> 3, g = c & 7;
      const float* wv = P.wpk + (size_t)(24 + (f * 3 + 1) * 8 + g) * CAP;
      float a = row_mac(P.sp_cols, wv, P.sp_ptr[r], P.sp_ptr[r + 1], P.zA2 + ((size_t)c << 15), lane);
      size_t idx = ((size_t)c << 15) + (r << 6) + lane;
      P.zB2[idx] = a; P.zacc[idx] += a;
    } else {
      int t = u - 32768; int g = t >> 9, r = t & 511;
      float a = row_mac(P.s_cols, P.s_vals, P.s_ptr[r], P.s_ptr[r + 1],
                        P.v1 + ((size_t)g << 15), lane);   // FIX: per-chain v1 offset
      P.v2[((size_t)g << 15) + (r << 6) + lane] = a;
    }
  }
  grid.sync();

  // ---- P9: L2 k2 (zacc += Phi2 zB2) + ht init ----
  for (int u = W; u < 32768; u += NWV) {
    int c = u >> 9, r = u & 511;
    int f = c >> 3, g = c & 7;
    const float* wv = P.wpk + (size_t)(24 + (f * 3 + 2) * 8 + g) * CAP;
    float a = row_mac(P.sp_cols, wv, P.sp_ptr[r], P.sp_ptr[r + 1], P.zB2 + ((size_t)c << 15), lane);
    size_t idx = ((size_t)c << 15) + (r << 6) + lane;
    P.zacc[idx] += a;
  }
  if (gtid < 32768) P.ht[gtid] = P.bW1[gtid >> 6];
  grid.sync();

  // ---- P10: y2 combine (sum over g of EV chains + LSI) ----
  for (int t = gtid; t < 262144; t += NTHR) {
    int f = t >> 15, mb = t & 32767;
    float r = P.b2[f];
#pragma unroll
    for (int g = 0; g < 8; ++g) {
      r += P.zacc[((size_t)(f * 8 + g) << 15) + mb];
      size_t gc = ((size_t)g << 15) + mb;
      r += P.wLSI2[f * 24 + g] * P.y1[gc] + P.wLSI2[f * 24 + 8 + g] * P.v1[gc]
         + P.wLSI2[f * 24 + 16 + g] * P.v2[gc];
    }
    P.y2[t] = r;
  }
  grid.sync();

  // ---- P11: gemm1 -> ht (512p x 64b), 4 q-slices per p, atomic reduce ----
  {
    int p = W >> 2, s = W & 3;
    int q0 = s << 10;
    const float* wrow = P.W1 + (size_t)p * 4096 + q0;
    float acc = 0.f;
    for (int q = 0; q < 1024; q += 8) {
#pragma unroll
      for (int i = 0; i < 8; ++i)
        acc += wrow[q + i] * P.y2[((size_t)(q0 + q + i) << 6) + lane];
    }
    atomicAdd(&P.ht[(p << 6) + lane], acc);
  }
  grid.sync();

  // ---- P12: gemm2 -> out (64b x 128o) ----
  if (W < 128) {
    int o = W;
    float acc = 0.f;
    for (int q = 0; q < 512; q += 8) {
#pragma unroll
      for (int i = 0; i < 8; ++i)
        acc += P.W2[(size_t)o * 512 + q + i] * P.ht[((q + i) << 6) + lane];
    }
    P.out[lane * 128 + o] = acc + P.bW2[o];
  }
}

extern "C" void kernel_launch(void* const* d_in, const int* in_sizes, int n_in,
                              void* d_out, int out_size, void* d_ws, size_t ws_size,
                              hipStream_t stream) {
  char* w = (char*)d_ws;
  auto alloc = [&](size_t bytes) { char* p = w; w += (bytes + 255) & ~(size_t)255; return p; };

  Params P;
  P.x     = (const float*)d_in[0];
  P.S     = (const float*)d_in[1];
  P.wEV1  = (const float*)d_in[2];
  P.wLSI1 = (const float*)d_in[3];
  P.b1    = (const float*)d_in[4];
  P.wEV2  = (const float*)d_in[5];
  P.wLSI2 = (const float*)d_in[6];
  P.b2    = (const float*)d_in[7];
  P.W1    = (const float*)d_in[8];
  P.bW1   = (const float*)d_in[9];
  P.W2    = (const float*)d_in[10];
  P.bW2   = (const float*)d_in[11];
  P.out   = (float*)d_out;

  P.sp_cnt  = (int*)alloc(512 * 4);
  P.s_cnt   = (int*)alloc(512 * 4);
  P.sp_ptr  = (int*)alloc(513 * 4);
  P.s_ptr   = (int*)alloc(513 * 4);
  P.sp_cols = (int*)alloc(CAP * 4);
  P.sp_rows = (int*)alloc(CAP * 4);
  P.s_cols  = (int*)alloc(CAP * 4);
  P.s_vals  = (float*)alloc(CAP * 4);
  P.wpk     = (float*)alloc((size_t)NPL * CAP * 4);       // 14.2 MB
  P.xt      = (float*)alloc((size_t)32768 * 4);
  P.u1      = (float*)alloc((size_t)32768 * 4);
  P.u2      = (float*)alloc((size_t)32768 * 4);
  P.zA1     = (float*)alloc((size_t)8 * 32768 * 4);
  P.zB1     = (float*)alloc((size_t)8 * 32768 * 4);
  P.y1      = (float*)alloc((size_t)8 * 32768 * 4);
  P.zA2     = (float*)alloc((size_t)64 * 32768 * 4);      // 8.4 MB
  P.zB2     = (float*)alloc((size_t)64 * 32768 * 4);
  P.zacc    = (float*)alloc((size_t)64 * 32768 * 4);
  P.v1      = (float*)alloc((size_t)8 * 32768 * 4);
  P.v2      = (float*)alloc((size_t)8 * 32768 * 4);
  P.y2      = (float*)alloc((size_t)8 * 32768 * 4);
  P.ht      = (float*)alloc((size_t)32768 * 4);
  (void)ws_size; (void)in_sizes; (void)n_in; (void)out_size;

  void* args[] = { &P };
  hipLaunchCooperativeKernel((const void*)mega, dim3(256), dim3(512), args, 0, stream);
}

// Round 5
// 902.752 us; speedup vs baseline: 1.2114x; 1.2114x over previous
//
#include <hip/hip_runtime.h>
#include <hip/hip_cooperative_groups.h>
#include <cstdint>
#include <cstddef>

namespace cg = cooperative_groups;

#define NNODE 512
#define MMASK 256
#define ZT 1e-9f

struct Params {
  const float *x, *S, *wEV1, *wLSI1, *b1, *wEV2, *wLSI2, *b2, *W1, *bW1, *W2, *bW2;
  float *out;
  int *sp_col, *sp_cnt, *s_col, *s_cnt;
  float *s_val, *xt, *u1, *u2, *zA1, *zB1, *y1, *zA2, *zB2, *v1, *v2, *y2, *ht;
};

// ELL row MAC: cl/wl are this lane's (col, weight) slot of row r (64 slots, pads cl=-1,wl=0).
// z addresses come from __shfl broadcasts -> all 16 z loads per chunk issued independently.
__device__ __forceinline__ float ell_mac(int cl, float wl, int cnt,
                                         const float* __restrict__ zin, int lane) {
  float acc = 0.f;
  for (int base = 0; base < cnt; base += 16) {
    float z[16];
#pragma unroll
    for (int i = 0; i < 16; ++i) {
      int c = __shfl(cl, base + i);
      z[i] = zin[((c < 0 ? 0 : c) << 6) + lane];   // 256B coalesced, mostly L2
    }
#pragma unroll
    for (int i = 0; i < 16; ++i) acc += __shfl(wl, base + i) * z[i];
  }
  return acc;
}

__global__ __launch_bounds__(512, 8) void mega(Params P) {
  cg::grid_group grid = cg::this_grid();
  const int tid = threadIdx.x;
  const int gtid = blockIdx.x * 512 + tid;
  const int nthr = gridDim.x << 9;
  const int nwv = nthr >> 6;
  const int W = gtid >> 6;
  const int lane = tid & 63;

  // ---- Ph0: ELL fill (one wave per row, ballot-compact, no scan) + x transpose ----
  if (W < NNODE) {
    int m = W;
    int csp = 0, cs = 0;
    unsigned long long lt = (1ull << lane) - 1ull;
    for (int ch = 0; ch < 8; ++ch) {
      int n = ch * 64 + lane;
      float s = P.S[m * NNODE + n];
      bool ps  = (s != 0.f);
      bool psp = ((fabsf(s) + ((m == n) ? 1.f : 0.f)) > ZT) && !((m >= MMASK) && (n >= MMASK));
      unsigned long long msp = __ballot(psp), ms = __ballot(ps);
      if (psp) { int p = csp + __popcll(msp & lt); if (p < 64) P.sp_col[(m << 6) + p] = n; }
      if (ps)  { int p = cs  + __popcll(ms  & lt); if (p < 64) { P.s_col[(m << 6) + p] = n; P.s_val[(m << 6) + p] = s; } }
      csp += __popcll(msp); cs += __popcll(ms);
    }
    if (lane >= csp) P.sp_col[(m << 6) + lane] = -1;
    if (lane >= cs)  { P.s_col[(m << 6) + lane] = -1; P.s_val[(m << 6) + lane] = 0.f; }
    if (lane == 0) { P.sp_cnt[m] = (csp < 64 ? csp : 64); P.s_cnt[m] = (cs < 64 ? cs : 64); }
  }
  if (gtid >= 32768 && gtid < 65536) {
    int t = gtid - 32768;
    int n = t >> 6, b = t & 63;
    P.xt[t] = P.x[b * NNODE + n];
  }
  grid.sync();

  // ---- Ph1: L1 k0 (zA1 = Phi0 x) + u1 = S x ----
  for (int u = W; u < 4608; u += nwv) {
    if (u < 4096) {
      int f = u >> 9, r = u & 511;
      const float* plane = P.wEV1 + ((size_t)(f * 3 + 0) << 18);
      int cl = P.sp_col[(r << 6) + lane];
      float wl = (cl >= 0) ? plane[(r << 9) + cl] : 0.f;
      float a = ell_mac(cl, wl, P.sp_cnt[r], P.xt, lane);
      P.zA1[((size_t)f << 15) + (r << 6) + lane] = a;
    } else {
      int r = u - 4096;
      int cl = P.s_col[(r << 6) + lane];
      float wl = P.s_val[(r << 6) + lane];
      float a = ell_mac(cl, wl, P.s_cnt[r], P.xt, lane);
      P.u1[(r << 6) + lane] = a;
    }
  }
  grid.sync();

  // ---- Ph2: L1 k1 (zB1 = Phi1 zA1) + u2 = S u1 ----
  for (int u = W; u < 4608; u += nwv) {
    if (u < 4096) {
      int f = u >> 9, r = u & 511;
      const float* plane = P.wEV1 + ((size_t)(f * 3 + 1) << 18);
      int cl = P.sp_col[(r << 6) + lane];
      float wl = (cl >= 0) ? plane[(r << 9) + cl] : 0.f;
      float a = ell_mac(cl, wl, P.sp_cnt[r], P.zA1 + ((size_t)f << 15), lane);
      P.zB1[((size_t)f << 15) + (r << 6) + lane] = a;
    } else {
      int r = u - 4096;
      int cl = P.s_col[(r << 6) + lane];
      float wl = P.s_val[(r << 6) + lane];
      float a = ell_mac(cl, wl, P.s_cnt[r], P.u1, lane);
      P.u2[(r << 6) + lane] = a;
    }
  }
  grid.sync();

  // ---- Ph3: L1 k2 + fused y1 combine ----
  for (int u = W; u < 4096; u += nwv) {
    int f = u >> 9, r = u & 511;
    const float* plane = P.wEV1 + ((size_t)(f * 3 + 2) << 18);
    int cl = P.sp_col[(r << 6) + lane];
    float wl = (cl >= 0) ? plane[(r << 9) + cl] : 0.f;
    float a = ell_mac(cl, wl, P.sp_cnt[r], P.zB1 + ((size_t)f << 15), lane);
    int idx = (r << 6) + lane;
    size_t fi = ((size_t)f << 15) + idx;
    P.y1[fi] = P.zA1[fi] + P.zB1[fi] + a
             + P.wLSI1[f * 3 + 0] * P.xt[idx] + P.wLSI1[f * 3 + 1] * P.u1[idx]
             + P.wLSI1[f * 3 + 2] * P.u2[idx] + P.b1[f];
  }
  grid.sync();

  // ---- Ph4: L2 k0 (zA2 = Phi0 y1_g) + v1 = S y1_g ----
  for (int u = W; u < 36864; u += nwv) {
    if (u < 32768) {
      int c = u >> 9, r = u & 511;
      int f = c >> 3, g = c & 7;
      const float* plane = P.wEV2 + ((size_t)((f * 3 + 0) * 8 + g) << 18);
      int cl = P.sp_col[(r << 6) + lane];
      float wl = (cl >= 0) ? plane[(r << 9) + cl] : 0.f;
      float a = ell_mac(cl, wl, P.sp_cnt[r], P.y1 + ((size_t)g << 15), lane);
      P.zA2[((size_t)c << 15) + (r << 6) + lane] = a;
    } else {
      int t = u - 32768;
      int g = t >> 9, r = t & 511;
      int cl = P.s_col[(r << 6) + lane];
      float wl = P.s_val[(r << 6) + lane];
      float a = ell_mac(cl, wl, P.s_cnt[r], P.y1 + ((size_t)g << 15), lane);
      P.v1[((size_t)g << 15) + (r << 6) + lane] = a;
    }
  }
  grid.sync();

  // ---- Ph5: L2 k1 (zB2 = Phi1 zA2) + v2 = S v1_g + y2 := b2 ----
  for (int u = W; u < 36864; u += nwv) {
    if (u < 32768) {
      int c = u >> 9, r = u & 511;
      int f = c >> 3, g = c & 7;
      const float* plane = P.wEV2 + ((size_t)((f * 3 + 1) * 8 + g) << 18);
      int cl = P.sp_col[(r << 6) + lane];
      float wl = (cl >= 0) ? plane[(r << 9) + cl] : 0.f;
      float a = ell_mac(cl, wl, P.sp_cnt[r], P.zA2 + ((size_t)c << 15), lane);
      P.zB2[((size_t)c << 15) + (r << 6) + lane] = a;
    } else {
      int t = u - 32768;
      int g = t >> 9, r = t & 511;
      int cl = P.s_col[(r << 6) + lane];
      float wl = P.s_val[(r << 6) + lane];
      float a = ell_mac(cl, wl, P.s_cnt[r], P.v1 + ((size_t)g << 15), lane);
      P.v2[((size_t)g << 15) + (r << 6) + lane] = a;
    }
  }
  for (int t = gtid; t < 262144; t += nthr) P.y2[t] = P.b2[t >> 15];
  grid.sync();

  // ---- Ph6: L2 k2 + fused per-(f,g) y2 contribution (atomic) + ht := bW1 ----
  for (int u = W; u < 32768; u += nwv) {
    int c = u >> 9, r = u & 511;
    int f = c >> 3, g = c & 7;
    const float* plane = P.wEV2 + ((size_t)((f * 3 + 2) * 8 + g) << 18);
    int cl = P.sp_col[(r << 6) + lane];
    float wl = (cl >= 0) ? plane[(r << 9) + cl] : 0.f;
    float a = ell_mac(cl, wl, P.sp_cnt[r], P.zB2 + ((size_t)c << 15), lane);
    int idx = (r << 6) + lane;
    size_t ci = ((size_t)c << 15) + idx;
    size_t gi = ((size_t)g << 15) + idx;
    float val = P.zA2[ci] + P.zB2[ci] + a
              + P.wLSI2[f * 24 + g]      * P.y1[gi]
              + P.wLSI2[f * 24 + 8 + g]  * P.v1[gi]
              + P.wLSI2[f * 24 + 16 + g] * P.v2[gi];
    atomicAdd(&P.y2[((size_t)f << 15) + idx], val);
  }
  if (gtid < 32768) P.ht[gtid] = P.bW1[gtid >> 6];
  grid.sync();

  // ---- Ph7: gemm1 -> ht (atomic over 32 q-slices) + out := bW2 ----
  if (gtid < 8192) P.out[gtid] = P.bW2[gtid & 127];
  for (int u = W; u < 2048; u += nwv) {
    int pg = u >> 5, qs = u & 31;
    const float* wrow = P.W1 + (size_t)pg * 8 * 4096 + qs * 128;
    const float* yb = P.y2 + ((size_t)(qs * 128) << 6);
    float acc[8] = {0, 0, 0, 0, 0, 0, 0, 0};
    for (int q = 0; q < 128; q += 8) {
      float yv[8];
#pragma unroll
      for (int i = 0; i < 8; ++i) yv[i] = yb[((q + i) << 6) + lane];
#pragma unroll
      for (int i = 0; i < 8; ++i) {
#pragma unroll
        for (int p = 0; p < 8; ++p) acc[p] += wrow[(size_t)p * 4096 + q + i] * yv[i];
      }
    }
#pragma unroll
    for (int p = 0; p < 8; ++p) atomicAdd(&P.ht[((pg * 8 + p) << 6) + lane], acc[p]);
  }
  grid.sync();

  // ---- Ph8: gemm2 -> out (atomic over 8 q-slices) ----
  for (int u = W; u < 1024; u += nwv) {
    int o = u >> 3, qs = u & 7;
    const float* w2 = P.W2 + (size_t)o * 512 + qs * 64;
    const float* hb = P.ht + ((size_t)(qs * 64) << 6);
    float acc = 0.f;
    for (int q = 0; q < 64; q += 8) {
#pragma unroll
      for (int i = 0; i < 8; ++i) acc += w2[q + i] * hb[((q + i) << 6) + lane];
    }
    atomicAdd(&P.out[lane * 128 + o], acc);
  }
}

extern "C" void kernel_launch(void* const* d_in, const int* in_sizes, int n_in,
                              void* d_out, int out_size, void* d_ws, size_t ws_size,
                              hipStream_t stream) {
  char* w = (char*)d_ws;
  auto alloc = [&](size_t bytes) { char* p = w; w += (bytes + 255) & ~(size_t)255; return p; };

  Params P;
  P.x     = (const float*)d_in[0];
  P.S     = (const float*)d_in[1];
  P.wEV1  = (const float*)d_in[2];
  P.wLSI1 = (const float*)d_in[3];
  P.b1    = (const float*)d_in[4];
  P.wEV2  = (const float*)d_in[5];
  P.wLSI2 = (const float*)d_in[6];
  P.b2    = (const float*)d_in[7];
  P.W1    = (const float*)d_in[8];
  P.bW1   = (const float*)d_in[9];
  P.W2    = (const float*)d_in[10];
  P.bW2   = (const float*)d_in[11];
  P.out   = (float*)d_out;

  P.sp_col = (int*)alloc(512 * 64 * 4);
  P.sp_cnt = (int*)alloc(512 * 4);
  P.s_col  = (int*)alloc(512 * 64 * 4);
  P.s_cnt  = (int*)alloc(512 * 4);
  P.s_val  = (float*)alloc(512 * 64 * 4);
  P.xt     = (float*)alloc((size_t)32768 * 4);
  P.u1     = (float*)alloc((size_t)32768 * 4);
  P.u2     = (float*)alloc((size_t)32768 * 4);
  P.zA1    = (float*)alloc((size_t)8 * 32768 * 4);
  P.zB1    = (float*)alloc((size_t)8 * 32768 * 4);
  P.y1     = (float*)alloc((size_t)8 * 32768 * 4);
  P.zA2    = (float*)alloc((size_t)64 * 32768 * 4);   // 8.4 MB
  P.zB2    = (float*)alloc((size_t)64 * 32768 * 4);
  P.v1     = (float*)alloc((size_t)8 * 32768 * 4);
  P.v2     = (float*)alloc((size_t)8 * 32768 * 4);
  P.y2     = (float*)alloc((size_t)8 * 32768 * 4);
  P.ht     = (float*)alloc((size_t)32768 * 4);
  (void)ws_size; (void)in_sizes; (void)n_in; (void)out_size;

  int maxb = 1;
  hipOccupancyMaxActiveBlocksPerMultiprocessor(&maxb, mega, 512, 0);
  if (maxb < 1) maxb = 1;
  if (maxb > 4) maxb = 4;
  int blocks = 256 * maxb;    // co-resident cooperative grid, up to 4 blocks/CU

  void* args[] = { &P };
  hipLaunchCooperativeKernel((const void*)mega, dim3(blocks), dim3(512), args, 0, stream);
}

// Round 6
// 492.526 us; speedup vs baseline: 2.2204x; 1.8329x over previous
//
#include <hip/hip_runtime.h>
#include <cstdint>
#include <cstddef>

#define NNODE 512
#define MMASK 256
#define ZT 1e-9f
#define NPL 216     // 24 L1 planes + 192 L2 planes

// ---------------- prep: ELL build (pad col=0, w=0) + x transpose ----------------
__global__ __launch_bounds__(256) void k_prep(const float* __restrict__ x,
                                              const float* __restrict__ S,
                                              int* __restrict__ sp_col, int* __restrict__ sp_cnt,
                                              int* __restrict__ s_col, float* __restrict__ s_val,
                                              int* __restrict__ s_cnt,
                                              float* __restrict__ xt) {
  int gtid = blockIdx.x * 256 + threadIdx.x;    // grid 128x256 = 32768
  int W = gtid >> 6, lane = threadIdx.x & 63;
  // transpose x: (B,N) -> (N,B)
  {
    int n = gtid >> 6, b = gtid & 63;
    xt[gtid] = x[b * NNODE + n];
  }
  // ELL fill, one wave per row
  int m = W;
  int csp = 0, cs = 0;
  unsigned long long lt = (1ull << lane) - 1ull;
  for (int ch = 0; ch < 8; ++ch) {
    int n = ch * 64 + lane;
    float s = S[m * NNODE + n];
    bool ps  = (s != 0.f);
    bool psp = ((fabsf(s) + ((m == n) ? 1.f : 0.f)) > ZT) && !((m >= MMASK) && (n >= MMASK));
    unsigned long long msp = __ballot(psp), ms = __ballot(ps);
    if (psp) { int p = csp + __popcll(msp & lt); if (p < 64) sp_col[(m << 6) + p] = n; }
    if (ps)  { int p = cs  + __popcll(ms  & lt); if (p < 64) { s_col[(m << 6) + p] = n; s_val[(m << 6) + p] = s; } }
    csp += __popcll(msp); cs += __popcll(ms);
  }
  if (lane >= csp) sp_col[(m << 6) + lane] = 0;                       // pad col -> 0
  if (lane >= cs)  { s_col[(m << 6) + lane] = 0; s_val[(m << 6) + lane] = 0.f; }
  if (lane == 0) { sp_cnt[m] = (csp < 64 ? csp : 64); s_cnt[m] = (cs < 64 ? cs : 64); }
}

// ---------------- pack: dense coalesced read of all planes -> ELL weights ------
__global__ __launch_bounds__(256) void k_pack(const float* __restrict__ wEV1,
                                              const float* __restrict__ wEV2,
                                              const int* __restrict__ sp_col,
                                              const int* __restrict__ sp_cnt,
                                              float* __restrict__ wpk) {
  __shared__ float rowbuf[4][512];
  int wv = threadIdx.x >> 6, lane = threadIdx.x & 63;
  int W = blockIdx.x * 4 + wv;
  int nwv = gridDim.x * 4;
  for (int job = W; job < NPL * NNODE; job += nwv) {
    int p = job >> 9, r = job & 511;
    const float* src = ((p < 24) ? (wEV1 + ((size_t)p << 18))
                                 : (wEV2 + ((size_t)(p - 24) << 18))) + (r << 9);
    // stage full 2KB row to LDS with two float4 wave-loads (coalesced, full BW)
    float4 a = ((const float4*)src)[lane];
    float4 b = ((const float4*)src)[64 + lane];
    ((float4*)rowbuf[wv])[lane] = a;
    ((float4*)rowbuf[wv])[64 + lane] = b;
    // same-wave LDS visibility: compiler inserts lgkmcnt wait
    int cl = sp_col[(r << 6) + lane];
    float wl = (lane < sp_cnt[r]) ? rowbuf[wv][cl] : 0.f;
    wpk[((size_t)p << 15) + (r << 6) + lane] = wl;
  }
}

// ---------------- ELL row MAC (pads: col 0, w 0) ----------------
__device__ __forceinline__ float ell_mac(int cl, float wl, int cnt,
                                         const float* __restrict__ zin, int lane) {
  float acc = 0.f;
  for (int base = 0; base < cnt; base += 16) {
    float z[16];
#pragma unroll
    for (int i = 0; i < 16; ++i) {
      int c = __shfl(cl, base + i);
      z[i] = zin[(c << 6) + lane];       // 256B coalesced, L2-resident
    }
#pragma unroll
    for (int i = 0; i < 16; ++i) acc += __shfl(wl, base + i) * z[i];
  }
  return acc;
}

// ---------------- layer 1 steps ----------------
__global__ __launch_bounds__(256) void k_l1s0(const float* __restrict__ wpk,
    const int* __restrict__ sp_col, const int* __restrict__ sp_cnt,
    const int* __restrict__ s_col, const float* __restrict__ s_val, const int* __restrict__ s_cnt,
    const float* __restrict__ xt, float* __restrict__ zA1, float* __restrict__ u1) {
  int W = (blockIdx.x * 256 + threadIdx.x) >> 6, lane = threadIdx.x & 63;
  int nwv = (gridDim.x << 2);
  for (int u = W; u < 4608; u += nwv) {
    if (u < 4096) {
      int f = u >> 9, r = u & 511;
      float wl = wpk[((size_t)(f * 3 + 0) << 15) + (r << 6) + lane];
      int cl = sp_col[(r << 6) + lane];
      zA1[((size_t)f << 15) + (r << 6) + lane] = ell_mac(cl, wl, sp_cnt[r], xt, lane);
    } else {
      int r = u - 4096;
      int cl = s_col[(r << 6) + lane];
      float wl = s_val[(r << 6) + lane];
      u1[(r << 6) + lane] = ell_mac(cl, wl, s_cnt[r], xt, lane);
    }
  }
}

__global__ __launch_bounds__(256) void k_l1s1(const float* __restrict__ wpk,
    const int* __restrict__ sp_col, const int* __restrict__ sp_cnt,
    const int* __restrict__ s_col, const float* __restrict__ s_val, const int* __restrict__ s_cnt,
    const float* __restrict__ zA1, const float* __restrict__ u1,
    float* __restrict__ zB1, float* __restrict__ u2) {
  int W = (blockIdx.x * 256 + threadIdx.x) >> 6, lane = threadIdx.x & 63;
  int nwv = (gridDim.x << 2);
  for (int u = W; u < 4608; u += nwv) {
    if (u < 4096) {
      int f = u >> 9, r = u & 511;
      float wl = wpk[((size_t)(f * 3 + 1) << 15) + (r << 6) + lane];
      int cl = sp_col[(r << 6) + lane];
      zB1[((size_t)f << 15) + (r << 6) + lane] =
          ell_mac(cl, wl, sp_cnt[r], zA1 + ((size_t)f << 15), lane);
    } else {
      int r = u - 4096;
      int cl = s_col[(r << 6) + lane];
      float wl = s_val[(r << 6) + lane];
      u2[(r << 6) + lane] = ell_mac(cl, wl, s_cnt[r], u1, lane);
    }
  }
}

__global__ __launch_bounds__(256) void k_l1s2(const float* __restrict__ wpk,
    const int* __restrict__ sp_col, const int* __restrict__ sp_cnt,
    const float* __restrict__ zA1, const float* __restrict__ zB1,
    const float* __restrict__ xt, const float* __restrict__ u1, const float* __restrict__ u2,
    const float* __restrict__ wLSI1, const float* __restrict__ b1, float* __restrict__ y1) {
  int W = (blockIdx.x * 256 + threadIdx.x) >> 6, lane = threadIdx.x & 63;
  int nwv = (gridDim.x << 2);
  for (int u = W; u < 4096; u += nwv) {
    int f = u >> 9, r = u & 511;
    float wl = wpk[((size_t)(f * 3 + 2) << 15) + (r << 6) + lane];
    int cl = sp_col[(r << 6) + lane];
    float a = ell_mac(cl, wl, sp_cnt[r], zB1 + ((size_t)f << 15), lane);
    int idx = (r << 6) + lane;
    size_t fi = ((size_t)f << 15) + idx;
    y1[fi] = zA1[fi] + zB1[fi] + a
           + wLSI1[f * 3 + 0] * xt[idx] + wLSI1[f * 3 + 1] * u1[idx]
           + wLSI1[f * 3 + 2] * u2[idx] + b1[f];
  }
}

// ---------------- layer 2 steps ----------------
__global__ __launch_bounds__(256) void k_l2s0(const float* __restrict__ wpk,
    const int* __restrict__ sp_col, const int* __restrict__ sp_cnt,
    const int* __restrict__ s_col, const float* __restrict__ s_val, const int* __restrict__ s_cnt,
    const float* __restrict__ y1, float* __restrict__ zA2, float* __restrict__ v1) {
  int W = (blockIdx.x * 256 + threadIdx.x) >> 6, lane = threadIdx.x & 63;
  int nwv = (gridDim.x << 2);
  for (int u = W; u < 36864; u += nwv) {
    if (u < 32768) {
      int c = u >> 9, r = u & 511;
      int f = c >> 3, g = c & 7;
      float wl = wpk[((size_t)(24 + (f * 3 + 0) * 8 + g) << 15) + (r << 6) + lane];
      int cl = sp_col[(r << 6) + lane];
      zA2[((size_t)c << 15) + (r << 6) + lane] =
          ell_mac(cl, wl, sp_cnt[r], y1 + ((size_t)g << 15), lane);
    } else {
      int t = u - 32768;
      int g = t >> 9, r = t & 511;
      int cl = s_col[(r << 6) + lane];
      float wl = s_val[(r << 6) + lane];
      v1[((size_t)g << 15) + (r << 6) + lane] =
          ell_mac(cl, wl, s_cnt[r], y1 + ((size_t)g << 15), lane);
    }
  }
}

__global__ __launch_bounds__(256) void k_l2s1(const float* __restrict__ wpk,
    const int* __restrict__ sp_col, const int* __restrict__ sp_cnt,
    const int* __restrict__ s_col, const float* __restrict__ s_val, const int* __restrict__ s_cnt,
    const float* __restrict__ zA2, const float* __restrict__ v1,
    float* __restrict__ zB2, float* __restrict__ v2) {
  int W = (blockIdx.x * 256 + threadIdx.x) >> 6, lane = threadIdx.x & 63;
  int nwv = (gridDim.x << 2);
  for (int u = W; u < 36864; u += nwv) {
    if (u < 32768) {
      int c = u >> 9, r = u & 511;
      int f = c >> 3, g = c & 7;
      float wl = wpk[((size_t)(24 + (f * 3 + 1) * 8 + g) << 15) + (r << 6) + lane];
      int cl = sp_col[(r << 6) + lane];
      zB2[((size_t)c << 15) + (r << 6) + lane] =
          ell_mac(cl, wl, sp_cnt[r], zA2 + ((size_t)c << 15), lane);
    } else {
      int t = u - 32768;
      int g = t >> 9, r = t & 511;
      int cl = s_col[(r << 6) + lane];
      float wl = s_val[(r << 6) + lane];
      v2[((size_t)g << 15) + (r << 6) + lane] =
          ell_mac(cl, wl, s_cnt[r], v1 + ((size_t)g << 15), lane);
    }
  }
}

// k2 step: one (f,r) job covers all 8 g -> direct y2 write, no atomics. ht init folded.
__global__ __launch_bounds__(256) void k_l2s2(const float* __restrict__ wpk,
    const int* __restrict__ sp_col, const int* __restrict__ sp_cnt,
    const float* __restrict__ zA2, const float* __restrict__ zB2,
    const float* __restrict__ y1, const float* __restrict__ v1, const float* __restrict__ v2,
    const float* __restrict__ wLSI2, const float* __restrict__ b2,
    const float* __restrict__ bW1, float* __restrict__ y2, float* __restrict__ ht) {
  int gtid = blockIdx.x * 256 + threadIdx.x;
  int W = gtid >> 6, lane = threadIdx.x & 63;
  int nwv = (gridDim.x << 2);
  if (gtid < 32768) ht[gtid] = bW1[gtid >> 6];
  for (int u = W; u < 4096; u += nwv) {
    int f = u >> 9, r = u & 511;
    int idx = (r << 6) + lane;
    int cl = sp_col[(r << 6) + lane];
    int cnt = sp_cnt[r];
    float acc = b2[f];
#pragma unroll
    for (int g = 0; g < 8; ++g) {
      int c = f * 8 + g;
      float wl = wpk[((size_t)(24 + (f * 3 + 2) * 8 + g) << 15) + (r << 6) + lane];
      float a = ell_mac(cl, wl, cnt, zB2 + ((size_t)c << 15), lane);
      size_t ci = ((size_t)c << 15) + idx;
      size_t gi = ((size_t)g << 15) + idx;
      acc += zA2[ci] + zB2[ci] + a
           + wLSI2[f * 24 + g]      * y1[gi]
           + wLSI2[f * 24 + 8 + g]  * v1[gi]
           + wLSI2[f * 24 + 16 + g] * v2[gi];
    }
    y2[((size_t)f << 15) + idx] = acc;
  }
}

// ---------------- readout ----------------
__global__ __launch_bounds__(256) void k_gemm1(const float* __restrict__ W1,
                                               const float* __restrict__ y2,
                                               const float* __restrict__ bW2,
                                               float* __restrict__ ht,
                                               float* __restrict__ out) {
  int gtid = blockIdx.x * 256 + threadIdx.x;   // grid 128x256
  int W = gtid >> 6, lane = threadIdx.x & 63;
  int nwv = (gridDim.x << 2);
  if (gtid < 8192) out[gtid] = bW2[gtid & 127];
  for (int u = W; u < 2048; u += nwv) {
    int pg = u >> 5, qs = u & 31;
    const float* wrow = W1 + (size_t)pg * 8 * 4096 + qs * 128;
    const float* yb = y2 + ((size_t)(qs * 128) << 6);
    float acc[8] = {0, 0, 0, 0, 0, 0, 0, 0};
    for (int q = 0; q < 128; q += 8) {
      float yv[8];
#pragma unroll
      for (int i = 0; i < 8; ++i) yv[i] = yb[((q + i) << 6) + lane];
#pragma unroll
      for (int i = 0; i < 8; ++i) {
#pragma unroll
        for (int p = 0; p < 8; ++p) acc[p] += wrow[(size_t)p * 4096 + q + i] * yv[i];
      }
    }
#pragma unroll
    for (int p = 0; p < 8; ++p) atomicAdd(&ht[((pg * 8 + p) << 6) + lane], acc[p]);
  }
}

__global__ __launch_bounds__(256) void k_gemm2(const float* __restrict__ W2,
                                               const float* __restrict__ ht,
                                               float* __restrict__ out) {
  int W = (blockIdx.x * 256 + threadIdx.x) >> 6, lane = threadIdx.x & 63;
  int nwv = (gridDim.x << 2);
  for (int u = W; u < 1024; u += nwv) {
    int o = u >> 3, qs = u & 7;
    const float* w2 = W2 + (size_t)o * 512 + qs * 64;
    const float* hb = ht + ((size_t)(qs * 64) << 6);
    float acc = 0.f;
    for (int q = 0; q < 64; q += 8) {
#pragma unroll
      for (int i = 0; i < 8; ++i) acc += w2[q + i] * hb[((q + i) << 6) + lane];
    }
    atomicAdd(&out[lane * 128 + o], acc);
  }
}

extern "C" void kernel_launch(void* const* d_in, const int* in_sizes, int n_in,
                              void* d_out, int out_size, void* d_ws, size_t ws_size,
                              hipStream_t stream) {
  const float* x     = (const float*)d_in[0];
  const float* S     = (const float*)d_in[1];
  const float* wEV1  = (const float*)d_in[2];
  const float* wLSI1 = (const float*)d_in[3];
  const float* b1    = (const float*)d_in[4];
  const float* wEV2  = (const float*)d_in[5];
  const float* wLSI2 = (const float*)d_in[6];
  const float* b2    = (const float*)d_in[7];
  const float* W1    = (const float*)d_in[8];
  const float* bW1   = (const float*)d_in[9];
  const float* W2    = (const float*)d_in[10];
  const float* bW2   = (const float*)d_in[11];
  float* out = (float*)d_out;

  char* w = (char*)d_ws;
  auto alloc = [&](size_t bytes) { char* p = w; w += (bytes + 255) & ~(size_t)255; return p; };
  int*   sp_col = (int*)alloc(512 * 64 * 4);
  int*   sp_cnt = (int*)alloc(512 * 4);
  int*   s_col  = (int*)alloc(512 * 64 * 4);
  float* s_val  = (float*)alloc(512 * 64 * 4);
  int*   s_cnt  = (int*)alloc(512 * 4);
  float* wpk    = (float*)alloc((size_t)NPL * 32768 * 4);   // 28.3 MB
  float* xt     = (float*)alloc((size_t)32768 * 4);
  float* u1     = (float*)alloc((size_t)32768 * 4);
  float* u2     = (float*)alloc((size_t)32768 * 4);
  float* zA1    = (float*)alloc((size_t)8 * 32768 * 4);
  float* zB1    = (float*)alloc((size_t)8 * 32768 * 4);
  float* y1     = (float*)alloc((size_t)8 * 32768 * 4);
  float* zA2    = (float*)alloc((size_t)64 * 32768 * 4);    // 8.4 MB
  float* zB2    = (float*)alloc((size_t)64 * 32768 * 4);
  float* v1     = (float*)alloc((size_t)8 * 32768 * 4);
  float* v2     = (float*)alloc((size_t)8 * 32768 * 4);
  float* y2     = (float*)alloc((size_t)8 * 32768 * 4);
  float* ht     = (float*)alloc((size_t)32768 * 4);
  (void)ws_size; (void)in_sizes; (void)n_in; (void)out_size;

  k_prep<<<128, 256, 0, stream>>>(x, S, sp_col, sp_cnt, s_col, s_val, s_cnt, xt);
  k_pack<<<1024, 256, 0, stream>>>(wEV1, wEV2, sp_col, sp_cnt, wpk);
  k_l1s0<<<256, 256, 0, stream>>>(wpk, sp_col, sp_cnt, s_col, s_val, s_cnt, xt, zA1, u1);
  k_l1s1<<<256, 256, 0, stream>>>(wpk, sp_col, sp_cnt, s_col, s_val, s_cnt, zA1, u1, zB1, u2);
  k_l1s2<<<256, 256, 0, stream>>>(wpk, sp_col, sp_cnt, zA1, zB1, xt, u1, u2, wLSI1, b1, y1);
  k_l2s0<<<1024, 256, 0, stream>>>(wpk, sp_col, sp_cnt, s_col, s_val, s_cnt, y1, zA2, v1);
  k_l2s1<<<1024, 256, 0, stream>>>(wpk, sp_col, sp_cnt, s_col, s_val, s_cnt, zA2, v1, zB2, v2);
  k_l2s2<<<512, 256, 0, stream>>>(wpk, sp_col, sp_cnt, zA2, zB2, y1, v1, v2, wLSI2, b2, bW1, y2, ht);
  k_gemm1<<<128, 256, 0, stream>>>(W1, y2, bW2, ht, out);
  k_gemm2<<<64, 256, 0, stream>>>(W2, ht, out);
}